// Round 6
// baseline (377.206 us; speedup 1.0000x reference)
//
#include <hip/hip_runtime.h>
#include <hip/hip_bf16.h>

// GraphNetwork GAT: B=4, N=2048, I=32, H=64, O=32, E=2, HD=2, D1=256
// R12: mac true-async loop (barrier -> issue stage(s+1) -> compute(s), so the
// DMA has the full compute phase in flight before the next barrier drains it);
// grid 1024 via etype split with XCD pairing (pair members 8 apart in hw
// order -> same XCD -> edges L2-hit); 8 waves = 2 heads x 4 k-quarters;
// LDS 48KB (sa2 16 + eds 2x16, sred aliased) -> 3 blocks/CU, 24 waves/CU.
// stats: NC=128, grid 2048. scale: 8-way parallel column sums.

constexpr int B_  = 4;
constexpr int N_  = 2048;
constexpr int I_  = 32;
constexpr int H_  = 64;
constexpr int O_  = 32;
constexpr int EH_ = 4;          // E*HD combos, c = e*2 + h
constexpr int D1_ = 256;        // H*HD*E
constexpr int BN_ = B_ * N_;    // 8192
constexpr int NC_ = 128;        // i-chunks for softmax stats
constexpr int CH_ = N_ / NC_;   // 16
constexpr int TI_ = 16;         // msg rows per block (one MFMA m-tile)
constexpr int TK_ = 32;         // k-tile (one MFMA K)
constexpr int NQT_ = 16;        // k-tiles per quarter (64 total / 4 kq)

typedef __bf16 bf16x8 __attribute__((ext_vector_type(8)));
typedef float floatx4 __attribute__((ext_vector_type(4)));

constexpr float L2E_ = 1.4426950408889634f;   // log2(e)

__device__ __forceinline__ unsigned short f2b(float f) {
    unsigned int u = __float_as_uint(f);
    return (unsigned short)((u + 0x7fffu + ((u >> 16) & 1u)) >> 16);
}

__device__ __forceinline__ float fexp2(float x) {
#if __has_builtin(__builtin_amdgcn_exp2f)
    return __builtin_amdgcn_exp2f(x);      // v_exp_f32 (exp2) direct
#else
    return __expf(x * 0.6931471805599453f);
#endif
}

// async global->LDS 16B per lane; dest = wave-uniform base + lane*16
__device__ __forceinline__ void gl2lds16(const void* g, void* l) {
    __builtin_amdgcn_global_load_lds(
        (const __attribute__((address_space(1))) unsigned int*)g,
        (__attribute__((address_space(3))) unsigned int*)l, 16, 0, 0);
}

// ------------------------------------------------- fused preprocessing
// blocks [0,2048): embed; [2048,2112): pack Wf0 (din=64); [2112,2368): Wf1
__global__ __launch_bounds__(256) void prep_kernel(
        const float* __restrict__ nodes, const float* __restrict__ W_emb,
        const float* __restrict__ b_emb, const float* __restrict__ Wf0,
        const float* __restrict__ Wf1, unsigned short* __restrict__ state0B,
        unsigned short* __restrict__ WfB0, unsigned short* __restrict__ WfB1) {
    int blk = blockIdx.x;
    int t = threadIdx.x;
    __shared__ float sn[4][I_];
    if (blk < 2048) {
        int r = t >> 6, h = t & 63;
        if (t < 4 * I_) {
            int rr = t / I_, ii = t % I_;
            sn[rr][ii] = nodes[(size_t)(blk * 4 + rr) * I_ + ii];
        }
        __syncthreads();
        float acc = b_emb[h];
        #pragma unroll
        for (int i = 0; i < I_; ++i) acc += sn[r][i] * W_emb[i * H_ + h];
        state0B[(size_t)(blk * 4 + r) * H_ + h] = f2b(acc);
    } else if (blk < 2048 + 64) {
        int o = (blk - 2048) * 256 + t;         // din=64
        int k = o & 63, n = (o >> 6) & 63, c = o >> 12;
        WfB0[o] = f2b(Wf0[((size_t)c * 64 + k) * 64 + n]);
    } else {
        int o = (blk - 2112) * 256 + t;         // din=256
        int k = o & 255, n = (o >> 8) & 63, c = o >> 14;
        WfB1[o] = f2b(Wf1[((size_t)c * 256 + k) * 64 + n]);
    }
}

// ---------------------------------------------------- Wh + a1/a2 via MFMA
// a1/a2 outputs are PRE-SCALED by log2(e) for the log2-domain softmax.
template <int DIN>
__global__ __launch_bounds__(256) void wh_a_mfma_kernel(
        const unsigned short* __restrict__ stateB, const unsigned short* __restrict__ WfB,
        const float* __restrict__ w1, const float* __restrict__ b1,
        const float* __restrict__ w2, const float* __restrict__ b2,
        unsigned short* __restrict__ WhB, float* __restrict__ a1,
        float* __restrict__ a2) {
    int t = threadIdx.x;
    int lane = t & 63, wv = t >> 6;             // wv = c
    int col = lane & 15, qd = lane >> 4;
    int bn0 = blockIdx.x * TI_;                 // grid BN/16 = 512
    int b = bn0 >> 11;

    floatx4 acc[4] = {{0,0,0,0},{0,0,0,0},{0,0,0,0},{0,0,0,0}};
    const unsigned short* __restrict__ ap = stateB + (size_t)(bn0 + col) * DIN + qd * 8;
    const unsigned short* __restrict__ bp = WfB + ((size_t)(wv * 64 + col) * DIN + qd * 8);
    #pragma unroll
    for (int k0 = 0; k0 < DIN; k0 += 32) {
        bf16x8 af = *(const bf16x8*)(ap + k0);
        #pragma unroll
        for (int nt = 0; nt < 4; ++nt) {
            bf16x8 bf = *(const bf16x8*)(bp + (size_t)nt * 16 * DIN + k0);
            acc[nt] = __builtin_amdgcn_mfma_f32_16x16x32_bf16(af, bf, acc[nt], 0, 0, 0);
        }
    }
    // acc[nt][r] = Wh[bn0 + qd*4 + r][nt*16 + col]
    int nb = ((bn0 & 2047) >> 3) + (qd >> 1);
    #pragma unroll
    for (int nt = 0; nt < 4; ++nt) {
        unsigned int lo = (unsigned int)f2b(acc[nt][0]) | ((unsigned int)f2b(acc[nt][1]) << 16);
        unsigned int hi = (unsigned int)f2b(acc[nt][2]) | ((unsigned int)f2b(acc[nt][3]) << 16);
        uint2 v = make_uint2(lo, hi);
        *(uint2*)(WhB + ((((size_t)(wv * B_ + b) * 256 + nb) * 64 + nt * 16 + col) * 8
                         + (qd & 1) * 4)) = v;
    }
    // a1/a2 row dots, butterfly over col lanes
    float p1[4] = {}, p2[4] = {};
    #pragma unroll
    for (int nt = 0; nt < 4; ++nt) {
        float w1n = w1[wv * H_ + nt * 16 + col];
        float w2n = w2[wv * H_ + nt * 16 + col];
        #pragma unroll
        for (int r = 0; r < 4; ++r) {
            p1[r] += acc[nt][r] * w1n;
            p2[r] += acc[nt][r] * w2n;
        }
    }
    #pragma unroll
    for (int m = 1; m < 16; m <<= 1)
        #pragma unroll
        for (int r = 0; r < 4; ++r) {
            p1[r] += __shfl_xor(p1[r], m, 64);
            p2[r] += __shfl_xor(p2[r], m, 64);
        }
    if (col == 0) {
        float b1c = b1[wv], b2c = b2[wv];
        #pragma unroll
        for (int r = 0; r < 4; ++r) {
            a1[(size_t)wv * BN_ + bn0 + qd * 4 + r] = (p1[r] + b1c) * L2E_;
            a2[(size_t)wv * BN_ + bn0 + qd * 4 + r] = (p2[r] + b2c) * L2E_;
        }
    }
}

// -------------------------------------------------- column softmax stats
// Direct sum-of-exp2 (range-safe). 2 j per thread, float4 edge loads.
// Grid B*NC*(N/512) = 2048 -> 8 blocks/CU, 32 waves/CU.
__global__ __launch_bounds__(256) void stats_kernel(
        const float* __restrict__ edges, const float* __restrict__ a1,
        const float* __restrict__ a2, float* __restrict__ ps) {
    int blk = blockIdx.x;
    int jt = blk & 3;                           // 4 j-tiles of 512
    int ic = (blk >> 2) & (NC_ - 1);
    int b  = blk >> 9;
    int t = threadIdx.x;
    int j0 = jt * 512 + t * 2;
    __shared__ float sa1[EH_][CH_];
    if (t < EH_ * CH_) {
        int cc = t >> 4, ii = t & 15;
        sa1[cc][ii] = a1[(size_t)cc * BN_ + b * N_ + ic * CH_ + ii];
    }
    __syncthreads();
    float a2x[EH_], a2y[EH_], s0[EH_], s1[EH_];
    #pragma unroll
    for (int cc = 0; cc < EH_; ++cc) {
        float2 av = *(const float2*)(a2 + (size_t)cc * BN_ + b * N_ + j0);
        a2x[cc] = av.x; a2y[cc] = av.y;
        s0[cc] = 0.f; s1[cc] = 0.f;
    }
    const float4* __restrict__ ep =
        (const float4*)edges + (((size_t)(b * N_ + ic * CH_) * N_ + j0) >> 1);
    #pragma unroll 4
    for (int ii = 0; ii < CH_; ++ii) {
        float4 u = ep[(size_t)ii * (N_ >> 1)];  // [e0 j0, e1 j0, e0 j1, e1 j1]
        #pragma unroll
        for (int cc = 0; cc < EH_; ++cc) {
            float base = sa1[cc][ii];
            float xa = base + a2x[cc];
            float xb = base + a2y[cc];
            float la = fmaxf(xa, 0.2f * xa);
            float lb = fmaxf(xb, 0.2f * xb);
            float ea = (cc < 2) ? u.x : u.y;
            float eb = (cc < 2) ? u.z : u.w;
            s0[cc] += fexp2(fmaf(ea, L2E_, la));
            s1[cc] += fexp2(fmaf(eb, L2E_, lb));
        }
    }
    #pragma unroll
    for (int cc = 0; cc < EH_; ++cc)
        *(float2*)&ps[((size_t)ic * EH_ + cc) * BN_ + b * N_ + j0] =
            make_float2(s0[cc], s1[cc]);
}

// ---------------------------------- fused combine + WhB denominator fold
// Each block: one (c,b), 32 consecutive k. 8 thread-groups sum 16 ic-chunks
// each, LDS-reduce, then all 256 threads scale one 8-ushort WhB chunk.
__global__ __launch_bounds__(256) void scale_kernel(
        const float* __restrict__ ps, unsigned short* __restrict__ WhB) {
    int t = threadIdx.x;
    int m0 = blockIdx.x * 256;              // chunk base, grid 1024
    int cb = m0 >> 14;
    int c = cb >> 2, b = cb & 3;
    int k0 = ((m0 >> 6) & 255) * 8;         // 32 consecutive k
    __shared__ float sP[8][32];
    __shared__ float sD[32];
    {
        int kk = t & 31, grp = t >> 5;
        float S = 0.f;
        const float* pp = ps + (size_t)c * BN_ + b * N_ + k0 + kk
                        + (size_t)grp * (NC_ / 8) * EH_ * BN_;
        #pragma unroll 4
        for (int ic = 0; ic < NC_ / 8; ++ic) S += pp[(size_t)ic * EH_ * BN_];
        sP[grp][kk] = S;
    }
    __syncthreads();
    if (t < 32) {
        float S = sP[0][t] + sP[1][t] + sP[2][t] + sP[3][t]
                + sP[4][t] + sP[5][t] + sP[6][t] + sP[7][t];
        sD[t] = 1.f / S;
    }
    __syncthreads();
    unsigned short* wp = WhB + (size_t)(m0 + t) * 8;
    uint4 w = *(const uint4*)wp;
    int nbo = (t >> 6) * 8;
    unsigned int words[4] = {w.x, w.y, w.z, w.w};
    #pragma unroll
    for (int q = 0; q < 4; ++q) {
        float lo = __uint_as_float((words[q] & 0xffffu) << 16) * sD[nbo + 2 * q];
        float hi = __uint_as_float(words[q] & 0xffff0000u) * sD[nbo + 2 * q + 1];
        words[q] = (unsigned)f2b(lo) | ((unsigned)f2b(hi) << 16);
    }
    *(uint4*)wp = make_uint4(words[0], words[1], words[2], words[3]);
}

// ------------------------------------------------------------- MFMA MAC
// Grid 1024: x=blk&7 (XCD), j=blk>>3; g = x*64 + (j>>1) (i-tile), cp = j&1
// (etype) -> the two blocks of a pair are 8 apart in hw order = same XCD,
// so the second's edge reads are L2 hits. 8 waves = (kq = wv>>1, cl = wv&1).
// Loop: barrier -> issue stage(s+1) (async DMA, swizzled source) ->
// compute kt = kq*16+s. a2 in LDS; denominator pre-folded into WhB.
// Epilogue: kq partials combined via LDS aliased over sa2/eds.
// LAST=0: state1B bf16 cols [cp*128,+128); LAST=1: po[cp*512+g][64]
template <int LAST>
__global__ __launch_bounds__(512, 6) void mac_kernel(
        const float* __restrict__ edges, const float* __restrict__ a1,
        const float* __restrict__ a2s, const unsigned short* __restrict__ WhB,
        const float* __restrict__ bias, void* __restrict__ outv) {
    int t = threadIdx.x;                    // 512
    int blk0 = blockIdx.x;                  // 1024
    int x = blk0 & 7, j = blk0 >> 3;
    int g  = x * 64 + (j >> 1);             // i-tile id 0..511
    int cp = j & 1;                         // etype
    int b  = g >> 7;
    int i0 = (g & 127) * TI_;
    int lane = t & 63, wv = t >> 6;
    int kq = wv >> 1;                       // k-quarter 0..3
    int cl = wv & 1;                        // head
    int c  = cp * 2 + cl;
    int col = lane & 15;                    // i offset (MFMA A row)
    int qd  = lane >> 4;                    // k subgroup (MFMA A k-quad)

    __shared__ __attribute__((aligned(16))) unsigned char smem[49152];
    float (*sa2)[N_] = (float(*)[N_])smem;          // [2][2048] = 16 KB
    unsigned char* eds = smem + 16384;              // [2][4][16][256] = 32 KB

    // stage a2 (pre-scaled by log2e) for this etype's two heads
    for (int q = t; q < 2 * (N_ / 4); q += 512) {
        int cl_ = q >> 9, kk = q & 511;
        ((float4*)sa2[cl_])[kk] =
            ((const float4*)(a2s + (size_t)(cp * 2 + cl_) * BN_ + b * N_))[kk];
    }

    float a1v = a1[(size_t)c * BN_ + b * N_ + i0 + col];          // pre-scaled
    const unsigned short* __restrict__ whb0 = WhB + (size_t)(c * B_ + b) * (N_ * 64);

    // staging role: wave wv stages tile T=kq, rows 8*cl + [0,8), 2 x 1KB
    int rowA = 8 * cl + (lane >> 4);
    int rowB = rowA + 4;
    const char* gr = (const char*)edges;
    size_t baseA = (size_t)(b * N_ + i0 + rowA) * N_ * 8
                 + (size_t)((lane & 15) ^ (rowA & 15)) * 16;
    size_t baseB = (size_t)(b * N_ + i0 + rowB) * N_ * 8
                 + (size_t)((lane & 15) ^ (rowB & 15)) * 16;
    unsigned char* ldA = eds + kq * 4096 + (8 * cl) * 256;
    unsigned char* ldB = ldA + 4 * 256;

    floatx4 acc[4] = {{0,0,0,0},{0,0,0,0},{0,0,0,0},{0,0,0,0}};

    {   // prologue: stage step 0 -> buf 0
        size_t ko = (size_t)(kq * NQT_) * 256;
        gl2lds16(gr + baseA + ko, ldA);
        gl2lds16(gr + baseB + ko, ldB);
    }
    for (int s = 0; s < NQT_; ++s) {
        __syncthreads();                    // publishes stage(s) [and sa2 @ s=0]
        if (s + 1 < NQT_) {                 // async stage(s+1), lands during compute
            int buf = (s + 1) & 1;
            size_t ko = (size_t)(kq * NQT_ + s + 1) * 256;
            gl2lds16(gr + baseA + ko, ldA + buf * 16384);
            gl2lds16(gr + baseB + ko, ldB + buf * 16384);
        }
        int kt = kq * NQT_ + s;
        const unsigned char* ebase = eds + (s & 1) * 16384 + kq * 4096 + col * 256;
        float ev[8];
        #pragma unroll
        for (int jj = 0; jj < 4; ++jj) {
            int sg = qd * 4 + jj;
            float4 v = *(const float4*)(ebase + (sg ^ col) * 16);
            ev[2 * jj]     = cp ? v.y : v.x;
            ev[2 * jj + 1] = cp ? v.w : v.z;
        }
        const float4* sp = (const float4*)&sa2[cl][kt * TK_ + qd * 8];
        float4 z0 = sp[0], z1 = sp[1];
        float az[8] = {z0.x, z0.y, z0.z, z0.w, z1.x, z1.y, z1.z, z1.w};
        bf16x8 bf[4];
        #pragma unroll
        for (int nt = 0; nt < 4; ++nt)
            bf[nt] = *(const bf16x8*)(whb0 + ((size_t)(kt * 4 + qd) * 64 + nt * 16 + col) * 8);
        bf16x8 af;
        #pragma unroll
        for (int jv = 0; jv < 8; ++jv) {
            float sx = a1v + az[jv];
            float u  = fmaxf(sx, 0.2f * sx);                 // lrelu (log2 dom.)
            af[jv] = (__bf16)fexp2(fmaf(ev[jv], L2E_, u));   // P (unnormalized)
        }
        #pragma unroll
        for (int nt = 0; nt < 4; ++nt)
            acc[nt] = __builtin_amdgcn_mfma_f32_16x16x32_bf16(af, bf[nt], acc[nt], 0, 0, 0);
    }

    // ---- combine kq partials; sred aliased over sa2/eds (safe post-barrier)
    __syncthreads();
    float (*sred)[2][TI_][H_ + 1] = (float(*)[2][TI_][H_ + 1])smem; // [3][2][16][65]
    if (kq > 0) {
        #pragma unroll
        for (int nt = 0; nt < 4; ++nt)
            #pragma unroll
            for (int r = 0; r < 4; ++r)
                sred[kq - 1][cl][qd * 4 + r][nt * 16 + col] = acc[nt][r];
    }
    __syncthreads();
    if (kq == 0) {
        if (LAST) {
            #pragma unroll
            for (int nt = 0; nt < 4; ++nt) {
                float bb = bias[cl * H_ + nt * 16 + col];
                #pragma unroll
                for (int r = 0; r < 4; ++r) {
                    float xv = acc[nt][r] + bb
                             + sred[0][cl][qd * 4 + r][nt * 16 + col]
                             + sred[1][cl][qd * 4 + r][nt * 16 + col]
                             + sred[2][cl][qd * 4 + r][nt * 16 + col];
                    sred[0][cl][qd * 4 + r][nt * 16 + col] =
                        xv > 0.f ? xv : (__expf(xv) - 1.f);  // elu
                }
            }
        } else {
            unsigned short* out = (unsigned short*)outv;
            #pragma unroll
            for (int nt = 0; nt < 4; ++nt) {
                float bb = bias[cl * H_ + nt * 16 + col];
                #pragma unroll
                for (int r = 0; r < 4; ++r) {
                    float xv = acc[nt][r] + bb
                             + sred[0][cl][qd * 4 + r][nt * 16 + col]
                             + sred[1][cl][qd * 4 + r][nt * 16 + col]
                             + sred[2][cl][qd * 4 + r][nt * 16 + col];
                    out[((size_t)(b * N_ + i0 + qd * 4 + r)) * D1_ + c * H_ + nt * 16 + col]
                        = f2b(xv);
                }
            }
        }
    }
    if (LAST) {
        __syncthreads();
        // block partial: sum elu over 16 rows and this etype's 2 heads
        if (t < 64) {
            float s = 0.f;
            #pragma unroll
            for (int r = 0; r < TI_; ++r)
                s += sred[0][0][r][t] + sred[0][1][r][t];
            ((float*)outv)[((size_t)cp * 512 + g) * 64 + t] = s * 0.25f;
        }
    }
}

// ------------------------------------------------------------- final output
// po[cp*512 + b*128 + it][64] partial row-sums -> out[b][o]
__global__ __launch_bounds__(1024) void out_kernel(
        const float* __restrict__ po, const float* __restrict__ W_out,
        const float* __restrict__ b_out, float* __restrict__ out) {
    int b = blockIdx.x, t = threadIdx.x;
    int d = t & 63, g0 = t >> 6;            // 16 groups
    float s = 0.f;
    #pragma unroll 4
    for (int p = g0; p < 256; p += 16) {
        int cp = p >> 7, it = p & 127;
        s += po[((size_t)cp * 512 + b * 128 + it) * 64 + d];
    }
    __shared__ float red[16][H_];
    red[g0][d] = s;
    __syncthreads();
    if (t < H_) {
        float r = 0.f;
        #pragma unroll
        for (int q = 0; q < 16; ++q) r += red[q][t];
        red[0][t] = r * (1.f / N_);
    }
    __syncthreads();
    if (t < O_) {
        float acc = b_out[t];
        #pragma unroll 8
        for (int dd = 0; dd < H_; ++dd)
            acc += red[0][dd] * W_out[dd * O_ + t];
        out[b * O_ + t] = acc;
    }
}

extern "C" void kernel_launch(void* const* d_in, const int* in_sizes, int n_in,
                              void* d_out, int out_size, void* d_ws, size_t ws_size,
                              hipStream_t stream) {
    const float* nodes = (const float*)d_in[0];
    const float* edges = (const float*)d_in[1];
    const float* W_emb = (const float*)d_in[2];
    const float* b_emb = (const float*)d_in[3];
    const float* Wf0   = (const float*)d_in[4];
    const float* w1_0  = (const float*)d_in[5];
    const float* b1_0  = (const float*)d_in[6];
    const float* w2_0  = (const float*)d_in[7];
    const float* b2_0  = (const float*)d_in[8];
    const float* bias0 = (const float*)d_in[9];
    const float* Wf1   = (const float*)d_in[10];
    const float* w1_1  = (const float*)d_in[11];
    const float* b1_1  = (const float*)d_in[12];
    const float* w2_1  = (const float*)d_in[13];
    const float* b2_1  = (const float*)d_in[14];
    const float* bias1 = (const float*)d_in[15];
    const float* W_out = (const float*)d_in[16];
    const float* b_out = (const float*)d_in[17];

    float* ws = (float*)d_ws;
    unsigned short* state0B = (unsigned short*)ws;                  // 262144 fl
    unsigned short* state1B = (unsigned short*)(ws + 262144);       // 1048576 fl
    unsigned short* WhB  = (unsigned short*)(ws + 262144 + 1048576);// 1048576 fl
    unsigned short* WfB0 = (unsigned short*)(ws + 2359296);         // 8192 fl
    unsigned short* WfB1 = (unsigned short*)(ws + 2367488);         // 32768 fl
    float* a1 = ws + 2400256;                                       // 32768 fl
    float* a2 = ws + 2433024;                                       // 32768 fl
    float* ps = ws + 2465792;                                       // NC*EH*BN = 4194304 fl
    float* po = ws + 6660096;                                       // 65536 fl

    prep_kernel<<<2368, 256, 0, stream>>>(nodes, W_emb, b_emb, Wf0, Wf1,
                                          state0B, WfB0, WfB1);

    // ---- layer 0
    wh_a_mfma_kernel<H_><<<BN_ / TI_, 256, 0, stream>>>(state0B, WfB0, w1_0, b1_0,
                                                        w2_0, b2_0, WhB, a1, a2);
    stats_kernel<<<B_ * NC_ * (N_ / 512), 256, 0, stream>>>(edges, a1, a2, ps);
    scale_kernel<<<1024, 256, 0, stream>>>(ps, WhB);
    mac_kernel<0><<<2 * B_ * (N_ / TI_), 512, 0, stream>>>(edges, a1, a2, WhB, bias0, state1B);
    // ---- layer 1
    wh_a_mfma_kernel<D1_><<<BN_ / TI_, 256, 0, stream>>>(state1B, WfB1, w1_1, b1_1,
                                                         w2_1, b2_1, WhB, a1, a2);
    stats_kernel<<<B_ * NC_ * (N_ / 512), 256, 0, stream>>>(edges, a1, a2, ps);
    scale_kernel<<<1024, 256, 0, stream>>>(ps, WhB);
    mac_kernel<1><<<2 * B_ * (N_ / TI_), 512, 0, stream>>>(edges, a1, a2, WhB, bias1, po);

    out_kernel<<<B_, 1024, 0, stream>>>(po, W_out, b_out, (float*)d_out);
}